// Round 2
// baseline (292.114 us; speedup 1.0000x reference)
//
#include <hip/hip_runtime.h>
#include <cstdint>
#include <cstddef>

typedef unsigned short u16;
typedef unsigned int   u32;
typedef __attribute__((ext_vector_type(8))) short bf16x8;
typedef __attribute__((ext_vector_type(4))) float f32x4;

#define D_IN  256
#define D_H   128
#define D_OUT 64

__device__ __forceinline__ float bf2f(u16 u){
  union { u32 i; float f; } v; v.i = ((u32)u) << 16; return v.f;
}
__device__ __forceinline__ u16 f2bf(float f){
  union { float f; u32 i; } v; v.f = f;
  u32 r = (v.i + 0x7fffu + ((v.i >> 16) & 1u)) >> 16;
  return (u16)r;
}

// ---------------- weight prep + deg zero (fused) ----------------
__global__ void k_wprep(const float* __restrict__ W0, const float* __restrict__ W1,
                        u16* __restrict__ W0t, u16* __restrict__ W1t,
                        int* __restrict__ deg, int n_t){
  int i = blockIdx.x * 256 + threadIdx.x;
  if (i < 128 * 256){
    int n = i >> 8, k = i & 255;
    W0t[i] = f2bf(W0[(size_t)k * 128 + n]);
  } else if (i < 128 * 256 + 64 * 128){
    int j = i - 128 * 256;
    int n = j >> 7, k = j & 127;
    W1t[j] = f2bf(W1[(size_t)k * 64 + n]);
  } else if (i - (128 * 256 + 64 * 128) < n_t){
    deg[i - (128 * 256 + 64 * 128)] = 0;
  }
}

// ---------------- graph prep ----------------
__global__ void k_deg(const int* __restrict__ dst, int E, int* __restrict__ deg){
  int e = blockIdx.x * 256 + threadIdx.x;
  if (e < E) atomicAdd(&deg[dst[e]], 1);
}

__global__ __launch_bounds__(256) void k_bsum(const int* __restrict__ deg, int N,
                                              int* __restrict__ bsum){
  __shared__ int s[256];
  int tid = threadIdx.x;
  int i = blockIdx.x * 256 + tid;
  s[tid] = (i < N) ? deg[i] : 0;
  __syncthreads();
  for (int o = 128; o > 0; o >>= 1){
    if (tid < o) s[tid] += s[tid + o];
    __syncthreads();
  }
  if (tid == 0) bsum[blockIdx.x] = s[0];
}

__global__ __launch_bounds__(256) void k_off(const int* __restrict__ deg, int N,
                                             const int* __restrict__ bsum, int nb,
                                             int* __restrict__ off, int* __restrict__ cursor,
                                             float* __restrict__ dinv){
  __shared__ int s[256];
  __shared__ int sbase[256];
  const int tid = threadIdx.x;
  const int bid = blockIdx.x;
  const int i   = bid * 256 + tid;
  int acc = 0;
  for (int j = tid; j < bid; j += 256) acc += bsum[j];
  sbase[tid] = acc;
  int v = (i < N) ? deg[i] : 0;
  s[tid] = v;
  __syncthreads();
  for (int o = 128; o > 0; o >>= 1){
    if (tid < o) sbase[tid] += sbase[tid + o];
    __syncthreads();
  }
  for (int o = 1; o < 256; o <<= 1){
    int t = (tid >= o) ? s[tid - o] : 0;
    __syncthreads();
    s[tid] += t;
    __syncthreads();
  }
  if (i < N){
    int excl = s[tid] - v + sbase[0];
    off[i] = excl;
    cursor[i] = excl;
    dinv[i] = rsqrtf((float)v + 1.0f);
  }
}

__global__ void k_fill(const int* __restrict__ src, const int* __restrict__ dst,
                       int E, int* __restrict__ cursor, int* __restrict__ csr){
  int e = blockIdx.x * 256 + threadIdx.x;
  if (e < E){
    int d = dst[e];
    int p = atomicAdd(&cursor[d], 1);
    csr[p] = src[e];
  }
}

// ---------------- GEMM1: streamed row staging + swizzled LDS ----------------
// Theory: X rows (1 KB HBM pages) must each be read ONCE as a contiguous
// wave-wide burst, not 8 temporally-scattered fragment visits (HBM row-buffer
// thrash capped both prior versions at ~2 TB/s effective).
// Block = 64 rows, full K. Stage: wave w iter i streams ENTIRE row (w+4i):
// 64 lanes x 16 B contiguous f32, convert to bf16, XOR-swizzled LDS write.
// Compute: waves split M (16 rows each), N=128 full; B global->reg dbuf (L2).
__global__ __launch_bounds__(256) void k_gemm1(
    const float* __restrict__ Xs, const float* __restrict__ Xt,
    const u16* __restrict__ W0t, int M, int n_s,
    u16* __restrict__ out)
{
  __shared__ u16 As[64 * 256];   // 32 KB, row r swizzled: off ^= (r&7)<<3 (u16 units)
  const int t    = threadIdx.x;
  const int wave = t >> 6, lane = t & 63;
  const int lm   = lane & 15, quad = lane >> 4;
  const int row0 = blockIdx.x * 64;

  // ---- stage 64 full rows (perfect streaming), f32 -> bf16, swizzled write ----
  {
    float4 st[16];
    #pragma unroll
    for (int i = 0; i < 16; i++){
      int r = row0 + wave + i * 4;
      const float* p;
      if (r < n_s)    p = Xs + (size_t)r * D_IN + lane * 4;
      else if (r < M) p = Xt + (size_t)(r - n_s) * D_IN + lane * 4;
      else            p = Xs + lane * 4;   // clamped; outputs guarded
      st[i] = *(const float4*)p;
    }
    #pragma unroll
    for (int i = 0; i < 16; i++){
      int r = wave + i * 4;                      // row within block
      u16 tmp[4];
      tmp[0] = f2bf(st[i].x); tmp[1] = f2bf(st[i].y);
      tmp[2] = f2bf(st[i].z); tmp[3] = f2bf(st[i].w);
      int c = (lane * 4) ^ ((r & 7) << 3);       // u16-unit offset within row
      *(int2*)&As[r * 256 + c] = *(const int2*)tmp;
    }
  }
  __syncthreads();

  // ---- compute: wave owns rows [wave*16, wave*16+16), all 128 cols ----
  f32x4 acc[8];
  const f32x4 z = {0.f, 0.f, 0.f, 0.f};
  #pragma unroll
  for (int nf = 0; nf < 8; nf++) acc[nf] = z;

  const u16* pb = W0t + (size_t)lm * D_IN + quad * 8;
  int4 b[2][8];
  #pragma unroll
  for (int nf = 0; nf < 8; nf++)
    b[0][nf] = *(const int4*)(pb + (size_t)nf * 16 * D_IN);

  const int ra  = wave * 16 + lm;
  const int rsw = (ra & 7) << 3;
  const u16* arow = As + ra * 256;

  #pragma unroll
  for (int kk = 0; kk < 8; kk++){
    const int cur = kk & 1, nxt = cur ^ 1;
    if (kk < 7){
      const int ko = (kk + 1) * 32;
      #pragma unroll
      for (int nf = 0; nf < 8; nf++)
        b[nxt][nf] = *(const int4*)(pb + (size_t)nf * 16 * D_IN + ko);
    }
    bf16x8 af = *(const bf16x8*)(arow + ((kk * 32 + quad * 8) ^ rsw));
    #pragma unroll
    for (int nf = 0; nf < 8; nf++)
      acc[nf] = __builtin_amdgcn_mfma_f32_16x16x32_bf16(
          af, *(const bf16x8*)&b[cur][nf], acc[nf], 0, 0, 0);
  }

  {
    int rbase = row0 + wave * 16 + quad * 4;
    #pragma unroll
    for (int rr = 0; rr < 4; rr++){
      int m = rbase + rr;
      if (m >= M) continue;
      u16* op = out + (size_t)m * D_H + lm;
      #pragma unroll
      for (int nf = 0; nf < 8; nf++)
        op[nf * 16] = f2bf(acc[nf][rr]);
    }
  }
}

// ---------------- fused aggregation (wide gather): one wave per dst node ----------------
__global__ __launch_bounds__(256) void k_aggf(
    const int* __restrict__ off, const int* __restrict__ deg,
    const int* __restrict__ csr, const float* __restrict__ dinv,
    u16* __restrict__ h1, int n_s, int n_t)
{
  int w    = (blockIdx.x * 256 + threadIdx.x) >> 6;
  int lane = threadIdx.x & 63;
  if (w >= n_t) return;
  const int g = lane >> 4;
  const int c = lane & 15;
  int start = off[w];
  int n     = deg[w];

  float r[8], p[8];
  #pragma unroll
  for (int q = 0; q < 8; q++){ r[q] = 0.f; p[q] = 0.f; }

  int i = 0;
  for (; i + 8 <= n; i += 8){
    int sa = csr[start + i + g];
    int sb = csr[start + i + 4 + g];
    int4 da = *(const int4*)(h1 + (size_t)sa * D_H + c * 8);
    int4 db = *(const int4*)(h1 + (size_t)sb * D_H + c * 8);
    const u16* ha = (const u16*)&da;
    const u16* hb = (const u16*)&db;
    #pragma unroll
    for (int q = 0; q < 8; q++){
      float va = bf2f(ha[q]), vb = bf2f(hb[q]);
      r[q] += va + vb;
      p[q] += fmaxf(va, 0.f) + fmaxf(vb, 0.f);
    }
  }
  for (; i < n; i += 4){
    if (i + g < n){
      int sa = csr[start + i + g];
      int4 da = *(const int4*)(h1 + (size_t)sa * D_H + c * 8);
      const u16* ha = (const u16*)&da;
      #pragma unroll
      for (int q = 0; q < 8; q++){
        float va = bf2f(ha[q]);
        r[q] += va;
        p[q] += fmaxf(va, 0.f);
      }
    }
  }

  #pragma unroll
  for (int q = 0; q < 8; q++){
    r[q] += __shfl_xor(r[q], 16, 64);
    r[q] += __shfl_xor(r[q], 32, 64);
    p[q] += __shfl_xor(p[q], 16, 64);
    p[q] += __shfl_xor(p[q], 32, 64);
  }

  if (g == 0){
    float di  = dinv[w];
    float di2 = di * di;
    u16* selfp = h1 + (size_t)(n_s + w) * D_H + c * 8;
    int4 hs = *(const int4*)selfp;
    const u16* hh = (const u16*)&hs;
    u16 ob[8];
    #pragma unroll
    for (int q = 0; q < 8; q++){
      float zq = fmaxf(di * r[q] + di2 * bf2f(hh[q]), 0.f);
      float uq = di * p[q] + di2 * zq;
      ob[q] = f2bf(uq);
    }
    *(int4*)selfp = *(int4*)ob;
  }
}

// ---------------- GEMM2: barrier-free, LDS-free. wave tile 32x64 ----------------
__device__ __forceinline__ bf16x8 relu_bf(int4 v, bool relu){
  const u16* s = (const u16*)&v;
  u16 tmp[8];
  #pragma unroll
  for (int q = 0; q < 8; q++){
    u16 x = s[q];
    tmp[q] = (relu && (x & 0x8000u)) ? (u16)0 : x;
  }
  return *(const bf16x8*)tmp;
}

__global__ __launch_bounds__(256) void k_gemm2(
    const u16* __restrict__ h1, const u16* __restrict__ W1t,
    int M, int n_s, float* __restrict__ out)
{
  const int t    = threadIdx.x;
  const int wave = t >> 6, lane = t & 63;
  const int lm   = lane & 15, quad = lane >> 4;
  const int rowW = blockIdx.x * 128 + wave * 32;

  int r0 = rowW + lm, r1 = rowW + 16 + lm;
  const bool relu0 = (r0 < n_s), relu1 = (r1 < n_s);
  int c0 = (r0 < M) ? r0 : 0, c1 = (r1 < M) ? r1 : 0;
  const u16* pa0 = h1 + (size_t)c0 * D_H + quad * 8;
  const u16* pa1 = h1 + (size_t)c1 * D_H + quad * 8;
  const u16* pb  = W1t + (size_t)lm * D_H + quad * 8;

  f32x4 acc[2][4];
  const f32x4 z = {0.f, 0.f, 0.f, 0.f};
  #pragma unroll
  for (int i = 0; i < 2; i++)
    #pragma unroll
    for (int j = 0; j < 4; j++) acc[i][j] = z;

  int4 a[2][2], b[2][4];
  a[0][0] = *(const int4*)(pa0);
  a[0][1] = *(const int4*)(pa1);
  #pragma unroll
  for (int nf = 0; nf < 4; nf++)
    b[0][nf] = *(const int4*)(pb + (size_t)nf * 16 * D_H);

  #pragma unroll
  for (int kk = 0; kk < 4; kk++){
    const int cur = kk & 1, nxt = cur ^ 1;
    if (kk < 3){
      const int ko = (kk + 1) * 32;
      a[nxt][0] = *(const int4*)(pa0 + ko);
      a[nxt][1] = *(const int4*)(pa1 + ko);
      #pragma unroll
      for (int nf = 0; nf < 4; nf++)
        b[nxt][nf] = *(const int4*)(pb + (size_t)nf * 16 * D_H + ko);
    }
    bf16x8 af[2];
    af[0] = relu_bf(a[cur][0], relu0);
    af[1] = relu_bf(a[cur][1], relu1);
    #pragma unroll
    for (int mi = 0; mi < 2; mi++)
      #pragma unroll
      for (int nf = 0; nf < 4; nf++)
        acc[mi][nf] = __builtin_amdgcn_mfma_f32_16x16x32_bf16(
            af[mi], *(const bf16x8*)&b[cur][nf], acc[mi][nf], 0, 0, 0);
  }

  #pragma unroll
  for (int mi = 0; mi < 2; mi++){
    int rbase = rowW + mi * 16 + quad * 4;
    #pragma unroll
    for (int rr = 0; rr < 4; rr++){
      int m = rbase + rr;
      if (m >= M) continue;
      float* op = out + (size_t)m * D_OUT + lm;
      #pragma unroll
      for (int nf = 0; nf < 4; nf++)
        op[nf * 16] = acc[mi][nf][rr];
    }
  }
}

static inline size_t alup(size_t x){ return (x + 255) & ~(size_t)255; }

extern "C" void kernel_launch(void* const* d_in, const int* in_sizes, int n_in,
                              void* d_out, int out_size, void* d_ws, size_t ws_size,
                              hipStream_t stream)
{
  const int*   ei = (const int*)d_in[0];
  const float* xs = (const float*)d_in[1];
  const float* xt = (const float*)d_in[2];
  const float* W0 = (const float*)d_in[3];
  const float* W1 = (const float*)d_in[4];
  const int E   = in_sizes[0] / 2;
  const int n_s = in_sizes[1] / D_IN;
  const int n_t = in_sizes[2] / D_IN;
  const int M   = n_s + n_t;
  const int* src = ei;       // edge_index row 0
  const int* dst = ei + E;   // edge_index row 1 (0-based target index)
  const int nb_t = (n_t + 255) / 256;

  // workspace layout (~29 MB)
  char* p = (char*)d_ws;
  int*   deg    = (int*)p;    p += alup((size_t)n_t * 4);
  int*   off    = (int*)p;    p += alup((size_t)n_t * 4);
  int*   cursor = (int*)p;    p += alup((size_t)n_t * 4);
  float* dinv   = (float*)p;  p += alup((size_t)n_t * 4);
  int*   bsum   = (int*)p;    p += alup((size_t)nb_t * 4);
  int*   csr    = (int*)p;    p += alup((size_t)E * 4);
  u16*   W0t    = (u16*)p;    p += alup((size_t)D_H * D_IN * 2);
  u16*   W1t    = (u16*)p;    p += alup((size_t)D_OUT * D_H * 2);
  u16*   h1     = (u16*)p;    p += alup((size_t)M * D_H * 2);

  const int wprep_n = 128*256 + 64*128 + n_t;
  k_wprep <<<(wprep_n + 255) / 256, 256, 0, stream>>>(W0, W1, W0t, W1t, deg, n_t);
  k_deg   <<<(E + 255) / 256, 256, 0, stream>>>(dst, E, deg);
  k_bsum  <<<nb_t, 256, 0, stream>>>(deg, n_t, bsum);
  k_off   <<<nb_t, 256, 0, stream>>>(deg, n_t, bsum, nb_t, off, cursor, dinv);
  k_fill  <<<(E + 255) / 256, 256, 0, stream>>>(src, dst, E, cursor, csr);

  // layer 1: h1 = X @ W0 (raw, all rows, bf16)
  k_gemm1<<<(M + 63) / 64, 256, 0, stream>>>(xs, xt, W0t, M, n_s, h1);
  // fused agg: h1 target rows <- u_t (single gather pass for both layers)
  k_aggf <<<(n_t + 3) / 4, 256, 0, stream>>>(off, deg, csr, dinv, h1, n_s, n_t);
  // layer 2: d_out = [relu(h1_s); u_t] @ W1  (final output)
  k_gemm2<<<(M + 127) / 128, 256, 0, stream>>>(h1, W1t, M, n_s, (float*)d_out);
}

// Round 3
// 260.767 us; speedup vs baseline: 1.1202x; 1.1202x over previous
//
#include <hip/hip_runtime.h>
#include <cstdint>
#include <cstddef>

typedef unsigned short u16;
typedef unsigned int   u32;
typedef __attribute__((ext_vector_type(8))) short bf16x8;
typedef __attribute__((ext_vector_type(4))) float f32x4;

#define D_IN  256
#define D_H   128
#define D_OUT 64

__device__ __forceinline__ float bf2f(u16 u){
  union { u32 i; float f; } v; v.i = ((u32)u) << 16; return v.f;
}
__device__ __forceinline__ u16 f2bf(float f){
  union { float f; u32 i; } v; v.f = f;
  u32 r = (v.i + 0x7fffu + ((v.i >> 16) & 1u)) >> 16;
  return (u16)r;
}

// ---------------- weight prep + deg zero (fused) ----------------
__global__ void k_wprep(const float* __restrict__ W0, const float* __restrict__ W1,
                        u16* __restrict__ W0t, u16* __restrict__ W1t,
                        int* __restrict__ deg, int n_t){
  int i = blockIdx.x * 256 + threadIdx.x;
  if (i < 128 * 256){
    int n = i >> 8, k = i & 255;
    W0t[i] = f2bf(W0[(size_t)k * 128 + n]);
  } else if (i < 128 * 256 + 64 * 128){
    int j = i - 128 * 256;
    int n = j >> 7, k = j & 127;
    W1t[j] = f2bf(W1[(size_t)k * 64 + n]);
  } else if (i - (128 * 256 + 64 * 128) < n_t){
    deg[i - (128 * 256 + 64 * 128)] = 0;
  }
}

// ---------------- graph prep ----------------
__global__ void k_deg(const int* __restrict__ dst, int E, int* __restrict__ deg){
  int e = blockIdx.x * 256 + threadIdx.x;
  if (e < E) atomicAdd(&deg[dst[e]], 1);
}

__global__ __launch_bounds__(256) void k_bsum(const int* __restrict__ deg, int N,
                                              int* __restrict__ bsum){
  __shared__ int s[256];
  int tid = threadIdx.x;
  int i = blockIdx.x * 256 + tid;
  s[tid] = (i < N) ? deg[i] : 0;
  __syncthreads();
  for (int o = 128; o > 0; o >>= 1){
    if (tid < o) s[tid] += s[tid + o];
    __syncthreads();
  }
  if (tid == 0) bsum[blockIdx.x] = s[0];
}

__global__ __launch_bounds__(256) void k_off(const int* __restrict__ deg, int N,
                                             const int* __restrict__ bsum, int nb,
                                             int* __restrict__ off, int* __restrict__ cursor,
                                             float* __restrict__ dinv){
  __shared__ int s[256];
  __shared__ int sbase[256];
  const int tid = threadIdx.x;
  const int bid = blockIdx.x;
  const int i   = bid * 256 + tid;
  int acc = 0;
  for (int j = tid; j < bid; j += 256) acc += bsum[j];
  sbase[tid] = acc;
  int v = (i < N) ? deg[i] : 0;
  s[tid] = v;
  __syncthreads();
  for (int o = 128; o > 0; o >>= 1){
    if (tid < o) sbase[tid] += sbase[tid + o];
    __syncthreads();
  }
  for (int o = 1; o < 256; o <<= 1){
    int t = (tid >= o) ? s[tid - o] : 0;
    __syncthreads();
    s[tid] += t;
    __syncthreads();
  }
  if (i < N){
    int excl = s[tid] - v + sbase[0];
    off[i] = excl;
    cursor[i] = excl;
    dinv[i] = rsqrtf((float)v + 1.0f);
  }
}

__global__ void k_fill(const int* __restrict__ src, const int* __restrict__ dst,
                       int E, int* __restrict__ cursor, int* __restrict__ csr){
  int e = blockIdx.x * 256 + threadIdx.x;
  if (e < E){
    int d = dst[e];
    int p = atomicAdd(&cursor[d], 1);
    csr[p] = src[e];
  }
}

// ---------------- GEMM1: persistent-B-in-LDS, barrier-free main loop ----------------
// Theory: all prior versions were stall-point-bound (barriers / B-load chains
// bunch memory traffic; CU memory pipe idles between phases). Here B (64 KB,
// L2-resident weights) is staged to swizzled LDS ONCE; then each of 8 waves
// independently streams its 16-row A strip: per K-step just 2 A-loads
// (depth-2 prefetch, 32 B/lane contiguous) + 8 swizzled ds_read_b128 + 8 MFMA.
// No barriers, no global B in steady state -> A loads stay in flight always.
__global__ __launch_bounds__(512, 3) void k_gemm1(
    const float* __restrict__ Xs, const float* __restrict__ Xt,
    const u16* __restrict__ W0t, int M, int n_s,
    u16* __restrict__ out)
{
  __shared__ u16 Bs[128 * 256];   // 64 KB; cell (n,kbyte) at n*512 + (kbyte ^ ((n&15)<<4))
  const int t    = threadIdx.x;
  const int wave = t >> 6, lane = t & 63;
  const int lm   = lane & 15, quad = lane >> 4;
  const int gw   = blockIdx.x * 8 + wave;   // global wave id
  const int row  = gw * 16 + lm;            // A row this lane reads

  int cr = (row < M) ? row : 0;
  const float* pa = ((cr < n_s) ? (Xs + (size_t)cr * D_IN)
                                : (Xt + (size_t)(cr - n_s) * D_IN)) + quad * 8;

  // issue A k-steps 0 and 1 before staging B (overlap HBM latency with staging)
  float4 a[2][2];
  a[0][0] = *(const float4*)(pa + 0);
  a[0][1] = *(const float4*)(pa + 4);
  a[1][0] = *(const float4*)(pa + 32);
  a[1][1] = *(const float4*)(pa + 36);

  // stage B once: thread t -> n = t>>2 (0..127), 128 B chunk c = t&3
  {
    const int n = t >> 2;
    const int c = t & 3;
    const u16* wsrc = W0t + (size_t)n * 256 + c * 64;
    char* brow = (char*)Bs + n * 512;
    const int sw = (n & 15) << 4;
    #pragma unroll
    for (int j = 0; j < 8; j++){
      int off = (c * 128 + j * 16) ^ sw;
      *(int4*)(brow + off) = *(const int4*)(wsrc + j * 8);
    }
  }
  __syncthreads();

  f32x4 acc[8];
  const f32x4 z = {0.f, 0.f, 0.f, 0.f};
  #pragma unroll
  for (int nf = 0; nf < 8; nf++) acc[nf] = z;

  const char* bb = (const char*)Bs + lm * 512;  // row base for this lane's lm
  const int lmx = lm << 4;

  #pragma unroll
  for (int kk = 0; kk < 8; kk++){
    const int cur = kk & 1;
    // convert current A frag (compiler waits only on these two loads)
    bf16x8 af;
    {
      const float* fa = (const float*)&a[cur][0];
      u16 tmp[8];
      #pragma unroll
      for (int q = 0; q < 8; q++) tmp[q] = f2bf(fa[q]);
      af = *(const bf16x8*)tmp;
    }
    // refill freed slot with k-step kk+2 (stays in flight across MFMAs)
    if (kk < 6){
      a[cur][0] = *(const float4*)(pa + (kk + 2) * 32);
      a[cur][1] = *(const float4*)(pa + (kk + 2) * 32 + 4);
    }
    const int koff = (kk * 64 + quad * 16) ^ lmx;   // swizzled in-row byte offset
    #pragma unroll
    for (int nf = 0; nf < 8; nf++){
      bf16x8 bf = *(const bf16x8*)(bb + nf * 8192 + koff);
      acc[nf] = __builtin_amdgcn_mfma_f32_16x16x32_bf16(af, bf, acc[nf], 0, 0, 0);
    }
  }

  {
    int rbase = gw * 16 + quad * 4;
    #pragma unroll
    for (int rr = 0; rr < 4; rr++){
      int m = rbase + rr;
      if (m >= M) continue;
      u16* op = out + (size_t)m * D_H + lm;
      #pragma unroll
      for (int nf = 0; nf < 8; nf++)
        op[nf * 16] = f2bf(acc[nf][rr]);
    }
  }
}

// ---------------- fused aggregation (wide gather): one wave per dst node ----------------
__global__ __launch_bounds__(256) void k_aggf(
    const int* __restrict__ off, const int* __restrict__ deg,
    const int* __restrict__ csr, const float* __restrict__ dinv,
    u16* __restrict__ h1, int n_s, int n_t)
{
  int w    = (blockIdx.x * 256 + threadIdx.x) >> 6;
  int lane = threadIdx.x & 63;
  if (w >= n_t) return;
  const int g = lane >> 4;
  const int c = lane & 15;
  int start = off[w];
  int n     = deg[w];

  float r[8], p[8];
  #pragma unroll
  for (int q = 0; q < 8; q++){ r[q] = 0.f; p[q] = 0.f; }

  int i = 0;
  for (; i + 8 <= n; i += 8){
    int sa = csr[start + i + g];
    int sb = csr[start + i + 4 + g];
    int4 da = *(const int4*)(h1 + (size_t)sa * D_H + c * 8);
    int4 db = *(const int4*)(h1 + (size_t)sb * D_H + c * 8);
    const u16* ha = (const u16*)&da;
    const u16* hb = (const u16*)&db;
    #pragma unroll
    for (int q = 0; q < 8; q++){
      float va = bf2f(ha[q]), vb = bf2f(hb[q]);
      r[q] += va + vb;
      p[q] += fmaxf(va, 0.f) + fmaxf(vb, 0.f);
    }
  }
  for (; i < n; i += 4){
    if (i + g < n){
      int sa = csr[start + i + g];
      int4 da = *(const int4*)(h1 + (size_t)sa * D_H + c * 8);
      const u16* ha = (const u16*)&da;
      #pragma unroll
      for (int q = 0; q < 8; q++){
        float va = bf2f(ha[q]);
        r[q] += va;
        p[q] += fmaxf(va, 0.f);
      }
    }
  }

  #pragma unroll
  for (int q = 0; q < 8; q++){
    r[q] += __shfl_xor(r[q], 16, 64);
    r[q] += __shfl_xor(r[q], 32, 64);
    p[q] += __shfl_xor(p[q], 16, 64);
    p[q] += __shfl_xor(p[q], 32, 64);
  }

  if (g == 0){
    float di  = dinv[w];
    float di2 = di * di;
    u16* selfp = h1 + (size_t)(n_s + w) * D_H + c * 8;
    int4 hs = *(const int4*)selfp;
    const u16* hh = (const u16*)&hs;
    u16 ob[8];
    #pragma unroll
    for (int q = 0; q < 8; q++){
      float zq = fmaxf(di * r[q] + di2 * bf2f(hh[q]), 0.f);
      float uq = di * p[q] + di2 * zq;
      ob[q] = f2bf(uq);
    }
    *(int4*)selfp = *(int4*)ob;
  }
}

// ---------------- GEMM2: same template (B=16 KB in LDS, barrier-free loop) ----------------
__device__ __forceinline__ bf16x8 relu_bf(int4 v, bool relu){
  const u16* s = (const u16*)&v;
  u16 tmp[8];
  #pragma unroll
  for (int q = 0; q < 8; q++){
    u16 x = s[q];
    tmp[q] = (relu && (x & 0x8000u)) ? (u16)0 : x;
  }
  return *(const bf16x8*)tmp;
}

__global__ __launch_bounds__(512, 3) void k_gemm2(
    const u16* __restrict__ h1, const u16* __restrict__ W1t,
    int M, int n_s, float* __restrict__ out)
{
  __shared__ u16 Bs[64 * 128];   // 16 KB; cell (n,kbyte) at n*256 + (kbyte ^ ((n&15)<<4))
  const int t    = threadIdx.x;
  const int wave = t >> 6, lane = t & 63;
  const int lm   = lane & 15, quad = lane >> 4;
  const int gw   = blockIdx.x * 8 + wave;
  const int row  = gw * 16 + lm;

  int cr = (row < M) ? row : 0;
  const bool relu = (row < n_s);
  const u16* pa = h1 + (size_t)cr * D_H + quad * 8;

  int4 a[2];
  a[0] = *(const int4*)(pa);
  a[1] = *(const int4*)(pa + 32);

  // stage B once: thread t -> n = t>>3 (0..63), 32 B chunk c = t&7
  {
    const int n = t >> 3;
    const int c = t & 7;
    const u16* wsrc = W1t + (size_t)n * 128 + c * 16;
    char* brow = (char*)Bs + n * 256;
    const int sw = (n & 15) << 4;
    #pragma unroll
    for (int j = 0; j < 2; j++){
      int off = (c * 32 + j * 16) ^ sw;
      *(int4*)(brow + off) = *(const int4*)(wsrc + j * 8);
    }
  }
  __syncthreads();

  f32x4 acc[4];
  const f32x4 z = {0.f, 0.f, 0.f, 0.f};
  #pragma unroll
  for (int nf = 0; nf < 4; nf++) acc[nf] = z;

  const char* bb = (const char*)Bs + lm * 256;
  const int lmx = lm << 4;

  #pragma unroll
  for (int kk = 0; kk < 4; kk++){
    const int cur = kk & 1;
    bf16x8 af = relu_bf(a[cur], relu);
    if (kk < 2)
      a[cur] = *(const int4*)(pa + (kk + 2) * 32);
    const int koff = (kk * 64 + quad * 16) ^ lmx;
    #pragma unroll
    for (int nf = 0; nf < 4; nf++){
      bf16x8 bf = *(const bf16x8*)(bb + nf * 4096 + koff);
      acc[nf] = __builtin_amdgcn_mfma_f32_16x16x32_bf16(af, bf, acc[nf], 0, 0, 0);
    }
  }

  {
    int rbase = gw * 16 + quad * 4;
    #pragma unroll
    for (int rr = 0; rr < 4; rr++){
      int m = rbase + rr;
      if (m >= M) continue;
      float* op = out + (size_t)m * D_OUT + lm;
      #pragma unroll
      for (int nf = 0; nf < 4; nf++)
        op[nf * 16] = acc[nf][rr];
    }
  }
}

static inline size_t alup(size_t x){ return (x + 255) & ~(size_t)255; }

extern "C" void kernel_launch(void* const* d_in, const int* in_sizes, int n_in,
                              void* d_out, int out_size, void* d_ws, size_t ws_size,
                              hipStream_t stream)
{
  const int*   ei = (const int*)d_in[0];
  const float* xs = (const float*)d_in[1];
  const float* xt = (const float*)d_in[2];
  const float* W0 = (const float*)d_in[3];
  const float* W1 = (const float*)d_in[4];
  const int E   = in_sizes[0] / 2;
  const int n_s = in_sizes[1] / D_IN;
  const int n_t = in_sizes[2] / D_IN;
  const int M   = n_s + n_t;
  const int* src = ei;       // edge_index row 0
  const int* dst = ei + E;   // edge_index row 1 (0-based target index)
  const int nb_t = (n_t + 255) / 256;

  // workspace layout (~29 MB)
  char* p = (char*)d_ws;
  int*   deg    = (int*)p;    p += alup((size_t)n_t * 4);
  int*   off    = (int*)p;    p += alup((size_t)n_t * 4);
  int*   cursor = (int*)p;    p += alup((size_t)n_t * 4);
  float* dinv   = (float*)p;  p += alup((size_t)n_t * 4);
  int*   bsum   = (int*)p;    p += alup((size_t)nb_t * 4);
  int*   csr    = (int*)p;    p += alup((size_t)E * 4);
  u16*   W0t    = (u16*)p;    p += alup((size_t)D_H * D_IN * 2);
  u16*   W1t    = (u16*)p;    p += alup((size_t)D_OUT * D_H * 2);
  u16*   h1     = (u16*)p;    p += alup((size_t)M * D_H * 2);

  const int wprep_n = 128*256 + 64*128 + n_t;
  k_wprep <<<(wprep_n + 255) / 256, 256, 0, stream>>>(W0, W1, W0t, W1t, deg, n_t);
  k_deg   <<<(E + 255) / 256, 256, 0, stream>>>(dst, E, deg);
  k_bsum  <<<nb_t, 256, 0, stream>>>(deg, n_t, bsum);
  k_off   <<<nb_t, 256, 0, stream>>>(deg, n_t, bsum, nb_t, off, cursor, dinv);
  k_fill  <<<(E + 255) / 256, 256, 0, stream>>>(src, dst, E, cursor, csr);

  // layer 1: h1 = X @ W0 (raw, all rows, bf16); 128 rows per 512-thread block
  k_gemm1<<<(M + 127) / 128, 512, 0, stream>>>(xs, xt, W0t, M, n_s, h1);
  // fused agg: h1 target rows <- u_t (single gather pass for both layers)
  k_aggf <<<(n_t + 3) / 4, 256, 0, stream>>>(off, deg, csr, dinv, h1, n_s, n_t);
  // layer 2: d_out = [relu(h1_s); u_t] @ W1  (final output)
  k_gemm2<<<(M + 127) / 128, 512, 0, stream>>>(h1, W1t, M, n_s, (float*)d_out);
}

// Round 5
// 255.611 us; speedup vs baseline: 1.1428x; 1.0202x over previous
//
#include <hip/hip_runtime.h>
#include <cstdint>
#include <cstddef>

typedef unsigned short u16;
typedef unsigned int   u32;
typedef __attribute__((ext_vector_type(8))) short bf16x8;
typedef __attribute__((ext_vector_type(4))) float f32x4;

#define D_IN  256
#define D_H   128
#define D_OUT 64

__device__ __forceinline__ float bf2f(u16 u){
  union { u32 i; float f; } v; v.i = ((u32)u) << 16; return v.f;
}
__device__ __forceinline__ u16 f2bf(float f){
  union { float f; u32 i; } v; v.f = f;
  u32 r = (v.i + 0x7fffu + ((v.i >> 16) & 1u)) >> 16;
  return (u16)r;
}

// ---------------- weight prep + deg zero (fused) ----------------
__global__ void k_wprep(const float* __restrict__ W0, const float* __restrict__ W1,
                        u16* __restrict__ W0t, u16* __restrict__ W1t,
                        int* __restrict__ deg, int n_t){
  int i = blockIdx.x * 256 + threadIdx.x;
  if (i < 128 * 256){
    int n = i >> 8, k = i & 255;
    W0t[i] = f2bf(W0[(size_t)k * 128 + n]);
  } else if (i < 128 * 256 + 64 * 128){
    int j = i - 128 * 256;
    int n = j >> 7, k = j & 127;
    W1t[j] = f2bf(W1[(size_t)k * 64 + n]);
  } else if (i - (128 * 256 + 64 * 128) < n_t){
    deg[i - (128 * 256 + 64 * 128)] = 0;
  }
}

// ---------------- graph prep ----------------
__global__ void k_deg(const int* __restrict__ dst, int E, int* __restrict__ deg){
  int e = blockIdx.x * 256 + threadIdx.x;
  if (e < E) atomicAdd(&deg[dst[e]], 1);
}

__global__ __launch_bounds__(256) void k_bsum(const int* __restrict__ deg, int N,
                                              int* __restrict__ bsum){
  __shared__ int s[256];
  int tid = threadIdx.x;
  int i = blockIdx.x * 256 + tid;
  s[tid] = (i < N) ? deg[i] : 0;
  __syncthreads();
  for (int o = 128; o > 0; o >>= 1){
    if (tid < o) s[tid] += s[tid + o];
    __syncthreads();
  }
  if (tid == 0) bsum[blockIdx.x] = s[0];
}

__global__ __launch_bounds__(256) void k_off(const int* __restrict__ deg, int N,
                                             const int* __restrict__ bsum, int nb,
                                             int* __restrict__ off, int* __restrict__ cursor,
                                             float* __restrict__ dinv){
  __shared__ int s[256];
  __shared__ int sbase[256];
  const int tid = threadIdx.x;
  const int bid = blockIdx.x;
  const int i   = bid * 256 + tid;
  int acc = 0;
  for (int j = tid; j < bid; j += 256) acc += bsum[j];
  sbase[tid] = acc;
  int v = (i < N) ? deg[i] : 0;
  s[tid] = v;
  __syncthreads();
  for (int o = 128; o > 0; o >>= 1){
    if (tid < o) sbase[tid] += sbase[tid + o];
    __syncthreads();
  }
  for (int o = 1; o < 256; o <<= 1){
    int t = (tid >= o) ? s[tid - o] : 0;
    __syncthreads();
    s[tid] += t;
    __syncthreads();
  }
  if (i < N){
    int excl = s[tid] - v + sbase[0];
    off[i] = excl;
    cursor[i] = excl;
    dinv[i] = rsqrtf((float)v + 1.0f);
  }
}

__global__ void k_fill(const int* __restrict__ src, const int* __restrict__ dst,
                       int E, int* __restrict__ cursor, int* __restrict__ csr){
  int e = blockIdx.x * 256 + threadIdx.x;
  if (e < E){
    int d = dst[e];
    int p = atomicAdd(&cursor[d], 1);
    csr[p] = src[e];
  }
}

// ---------------- GEMM1: persistent-B LDS + FULL-ROW A prefetch ----------------
// Steady-state loop has ZERO global loads and ZERO barriers: each lane issues
// all 16 dwordx4 A-loads (its whole K=256 row) in the prologue; the unrolled
// loop drains them with counted vmcnt waits. Latency exposure -> one initial
// fill only. B (64 KB weights) staged once to XOR-swizzled LDS.
// VGPR budget: 64 (A ring) + 32 (acc) + temps ~= 120 -> 4 waves/SIMD with
// __launch_bounds__(512,4); LDS 64 KB -> 2 blocks/CU = 16 waves/CU.
__global__ __launch_bounds__(512, 4) void k_gemm1(
    const float* __restrict__ Xs, const float* __restrict__ Xt,
    const u16* __restrict__ W0t, int M, int n_s,
    u16* __restrict__ out)
{
  __shared__ u16 Bs[128 * 256];   // 64 KB; cell (n,kbyte) at n*512 + (kbyte ^ ((n&15)<<4))
  const int t    = threadIdx.x;
  const int wave = t >> 6, lane = t & 63;
  const int lm   = lane & 15, quad = lane >> 4;
  const int gw   = blockIdx.x * 8 + wave;   // global wave id
  const int row  = gw * 16 + lm;            // A row this lane reads

  int cr = (row < M) ? row : 0;
  const float* pa = ((cr < n_s) ? (Xs + (size_t)cr * D_IN)
                                : (Xt + (size_t)(cr - n_s) * D_IN)) + quad * 8;

  float4 a[8][2];
  // issue first 2 K-steps before staging (overlap HBM latency with stage)
  a[0][0] = *(const float4*)(pa +  0); a[0][1] = *(const float4*)(pa +  4);
  a[1][0] = *(const float4*)(pa + 32); a[1][1] = *(const float4*)(pa + 36);

  // stage B once: thread t -> n = t>>2 (0..127), 128 B chunk c = t&3
  {
    const int n = t >> 2;
    const int c = t & 3;
    const u16* wsrc = W0t + (size_t)n * 256 + c * 64;
    char* brow = (char*)Bs + n * 512;
    const int sw = (n & 15) << 4;
    #pragma unroll
    for (int j = 0; j < 8; j++){
      int off = (c * 128 + j * 16) ^ sw;
      *(int4*)(brow + off) = *(const int4*)(wsrc + j * 8);
    }
  }

  // issue remaining 6 K-steps (stage regs are dead by now)
  #pragma unroll
  for (int s = 2; s < 8; s++){
    a[s][0] = *(const float4*)(pa + s * 32);
    a[s][1] = *(const float4*)(pa + s * 32 + 4);
  }

  f32x4 acc[8];
  const f32x4 z = {0.f, 0.f, 0.f, 0.f};
  #pragma unroll
  for (int nf = 0; nf < 8; nf++) acc[nf] = z;

  __syncthreads();

  const char* bb = (const char*)Bs + lm * 512;  // B row base for this lane's lm
  const int lmx = lm << 4;

  #pragma unroll
  for (int kk = 0; kk < 8; kk++){
    bf16x8 af;
    {
      const float* fa = (const float*)&a[kk][0];
      u16 tmp[8];
      #pragma unroll
      for (int q = 0; q < 8; q++) tmp[q] = f2bf(fa[q]);
      af = *(const bf16x8*)tmp;
    }
    const int koff = (kk * 64 + quad * 16) ^ lmx;   // swizzled in-row byte offset
    #pragma unroll
    for (int nf = 0; nf < 8; nf++){
      bf16x8 bf = *(const bf16x8*)(bb + nf * 8192 + koff);
      acc[nf] = __builtin_amdgcn_mfma_f32_16x16x32_bf16(af, bf, acc[nf], 0, 0, 0);
    }
  }

  {
    int rbase = gw * 16 + quad * 4;
    #pragma unroll
    for (int rr = 0; rr < 4; rr++){
      int m = rbase + rr;
      if (m >= M) continue;
      u16* op = out + (size_t)m * D_H + lm;
      #pragma unroll
      for (int nf = 0; nf < 8; nf++)
        op[nf * 16] = f2bf(acc[nf][rr]);
    }
  }
}

// ---------------- fused aggregation (wide gather): one wave per dst node ----------------
__global__ __launch_bounds__(256) void k_aggf(
    const int* __restrict__ off, const int* __restrict__ deg,
    const int* __restrict__ csr, const float* __restrict__ dinv,
    u16* __restrict__ h1, int n_s, int n_t)
{
  int w    = (blockIdx.x * 256 + threadIdx.x) >> 6;
  int lane = threadIdx.x & 63;
  if (w >= n_t) return;
  const int g = lane >> 4;
  const int c = lane & 15;
  int start = off[w];
  int n     = deg[w];

  float r[8], p[8];
  #pragma unroll
  for (int q = 0; q < 8; q++){ r[q] = 0.f; p[q] = 0.f; }

  int i = 0;
  for (; i + 8 <= n; i += 8){
    int sa = csr[start + i + g];
    int sb = csr[start + i + 4 + g];
    int4 da = *(const int4*)(h1 + (size_t)sa * D_H + c * 8);
    int4 db = *(const int4*)(h1 + (size_t)sb * D_H + c * 8);
    const u16* ha = (const u16*)&da;
    const u16* hb = (const u16*)&db;
    #pragma unroll
    for (int q = 0; q < 8; q++){
      float va = bf2f(ha[q]), vb = bf2f(hb[q]);
      r[q] += va + vb;
      p[q] += fmaxf(va, 0.f) + fmaxf(vb, 0.f);
    }
  }
  for (; i < n; i += 4){
    if (i + g < n){
      int sa = csr[start + i + g];
      int4 da = *(const int4*)(h1 + (size_t)sa * D_H + c * 8);
      const u16* ha = (const u16*)&da;
      #pragma unroll
      for (int q = 0; q < 8; q++){
        float va = bf2f(ha[q]);
        r[q] += va;
        p[q] += fmaxf(va, 0.f);
      }
    }
  }

  #pragma unroll
  for (int q = 0; q < 8; q++){
    r[q] += __shfl_xor(r[q], 16, 64);
    r[q] += __shfl_xor(r[q], 32, 64);
    p[q] += __shfl_xor(p[q], 16, 64);
    p[q] += __shfl_xor(p[q], 32, 64);
  }

  if (g == 0){
    float di  = dinv[w];
    float di2 = di * di;
    u16* selfp = h1 + (size_t)(n_s + w) * D_H + c * 8;
    int4 hs = *(const int4*)selfp;
    const u16* hh = (const u16*)&hs;
    u16 ob[8];
    #pragma unroll
    for (int q = 0; q < 8; q++){
      float zq = fmaxf(di * r[q] + di2 * bf2f(hh[q]), 0.f);
      float uq = di * p[q] + di2 * zq;
      ob[q] = f2bf(uq);
    }
    *(int4*)selfp = *(int4*)ob;
  }
}

// ---------------- GEMM2: same template (B=16 KB LDS, full-K A prefetch) ----------------
__device__ __forceinline__ bf16x8 relu_bf(int4 v, bool relu){
  const u16* s = (const u16*)&v;
  u16 tmp[8];
  #pragma unroll
  for (int q = 0; q < 8; q++){
    u16 x = s[q];
    tmp[q] = (relu && (x & 0x8000u)) ? (u16)0 : x;
  }
  return *(const bf16x8*)tmp;
}

__global__ __launch_bounds__(512, 4) void k_gemm2(
    const u16* __restrict__ h1, const u16* __restrict__ W1t,
    int M, int n_s, float* __restrict__ out)
{
  __shared__ u16 Bs[64 * 128];   // 16 KB; cell (n,kbyte) at n*256 + (kbyte ^ ((n&15)<<4))
  const int t    = threadIdx.x;
  const int wave = t >> 6, lane = t & 63;
  const int lm   = lane & 15, quad = lane >> 4;
  const int gw   = blockIdx.x * 8 + wave;
  const int row  = gw * 16 + lm;

  int cr = (row < M) ? row : 0;
  const bool relu = (row < n_s);
  const u16* pa = h1 + (size_t)cr * D_H + quad * 8;

  // full-K A prefetch: 4 int4, zero loads in the loop
  int4 a[4];
  a[0] = *(const int4*)(pa);
  a[1] = *(const int4*)(pa + 32);

  // stage B once: thread t -> n = t>>3 (0..63), 32 B chunk c = t&7
  {
    const int n = t >> 3;
    const int c = t & 7;
    const u16* wsrc = W1t + (size_t)n * 128 + c * 16;
    char* brow = (char*)Bs + n * 256;
    const int sw = (n & 15) << 4;
    #pragma unroll
    for (int j = 0; j < 2; j++){
      int off = (c * 32 + j * 16) ^ sw;
      *(int4*)(brow + off) = *(const int4*)(wsrc + j * 8);
    }
  }
  a[2] = *(const int4*)(pa + 64);
  a[3] = *(const int4*)(pa + 96);

  f32x4 acc[4];
  const f32x4 z = {0.f, 0.f, 0.f, 0.f};
  #pragma unroll
  for (int nf = 0; nf < 4; nf++) acc[nf] = z;

  __syncthreads();

  const char* bb = (const char*)Bs + lm * 256;
  const int lmx = lm << 4;

  #pragma unroll
  for (int kk = 0; kk < 4; kk++){
    bf16x8 af = relu_bf(a[kk], relu);
    const int koff = (kk * 64 + quad * 16) ^ lmx;
    #pragma unroll
    for (int nf = 0; nf < 4; nf++){
      bf16x8 bf = *(const bf16x8*)(bb + nf * 4096 + koff);
      acc[nf] = __builtin_amdgcn_mfma_f32_16x16x32_bf16(af, bf, acc[nf], 0, 0, 0);
    }
  }

  {
    int rbase = gw * 16 + quad * 4;
    #pragma unroll
    for (int rr = 0; rr < 4; rr++){
      int m = rbase + rr;
      if (m >= M) continue;
      float* op = out + (size_t)m * D_OUT + lm;
      #pragma unroll
      for (int nf = 0; nf < 4; nf++)
        op[nf * 16] = acc[nf][rr];
    }
  }
}

static inline size_t alup(size_t x){ return (x + 255) & ~(size_t)255; }

extern "C" void kernel_launch(void* const* d_in, const int* in_sizes, int n_in,
                              void* d_out, int out_size, void* d_ws, size_t ws_size,
                              hipStream_t stream)
{
  const int*   ei = (const int*)d_in[0];
  const float* xs = (const float*)d_in[1];
  const float* xt = (const float*)d_in[2];
  const float* W0 = (const float*)d_in[3];
  const float* W1 = (const float*)d_in[4];
  const int E   = in_sizes[0] / 2;
  const int n_s = in_sizes[1] / D_IN;
  const int n_t = in_sizes[2] / D_IN;
  const int M   = n_s + n_t;
  const int* src = ei;       // edge_index row 0
  const int* dst = ei + E;   // edge_index row 1 (0-based target index)
  const int nb_t = (n_t + 255) / 256;

  // workspace layout (~29 MB)
  char* p = (char*)d_ws;
  int*   deg    = (int*)p;    p += alup((size_t)n_t * 4);
  int*   off    = (int*)p;    p += alup((size_t)n_t * 4);
  int*   cursor = (int*)p;    p += alup((size_t)n_t * 4);
  float* dinv   = (float*)p;  p += alup((size_t)n_t * 4);
  int*   bsum   = (int*)p;    p += alup((size_t)nb_t * 4);
  int*   csr    = (int*)p;    p += alup((size_t)E * 4);
  u16*   W0t    = (u16*)p;    p += alup((size_t)D_H * D_IN * 2);
  u16*   W1t    = (u16*)p;    p += alup((size_t)D_OUT * D_H * 2);
  u16*   h1     = (u16*)p;    p += alup((size_t)M * D_H * 2);

  const int wprep_n = 128*256 + 64*128 + n_t;
  k_wprep <<<(wprep_n + 255) / 256, 256, 0, stream>>>(W0, W1, W0t, W1t, deg, n_t);
  k_deg   <<<(E + 255) / 256, 256, 0, stream>>>(dst, E, deg);
  k_bsum  <<<nb_t, 256, 0, stream>>>(deg, n_t, bsum);
  k_off   <<<nb_t, 256, 0, stream>>>(deg, n_t, bsum, nb_t, off, cursor, dinv);
  k_fill  <<<(E + 255) / 256, 256, 0, stream>>>(src, dst, E, cursor, csr);

  // layer 1: h1 = X @ W0 (raw, all rows, bf16); 128 rows per 512-thread block
  k_gemm1<<<(M + 127) / 128, 512, 0, stream>>>(xs, xt, W0t, M, n_s, h1);
  // fused agg: h1 target rows <- u_t (single gather pass for both layers)
  k_aggf <<<(n_t + 3) / 4, 256, 0, stream>>>(off, deg, csr, dinv, h1, n_s, n_t);
  // layer 2: d_out = [relu(h1_s); u_t] @ W1  (final output)
  k_gemm2<<<(M + 127) / 128, 512, 0, stream>>>(h1, W1t, M, n_s, (float*)d_out);
}